// Round 13
// baseline (73.544 us; speedup 1.0000x reference)
//
#include <hip/hip_runtime.h>
#include <stdint.h>

#define IN_F 4096
#define OUT_F 11008
#define M_ROWS 256
#define RANK 16
#define NWORDS 256           // packed words per T row

#define BM 128
#define BN 64
#define BK 64
#define KSPLIT 2
#define K_PER 2048
#define NIT 32               // K_PER / BK

typedef unsigned short u16;
typedef __attribute__((ext_vector_type(8))) short short8;
typedef __attribute__((ext_vector_type(4))) float floatx4;

__device__ __forceinline__ u16 f32_to_bf16_rne(float f) {
    uint32_t u = __builtin_bit_cast(uint32_t, f);
    uint32_t r = (u + 0x7FFFu + ((u >> 16) & 1u)) >> 16;
    return (u16)r;
}

// ---------------- prep: rowsum, lora_xA, x->bf16 (VERIFIED) ----------------
__global__ __launch_bounds__(256) void prep_kernel(
    const float* __restrict__ x, const float* __restrict__ lora_A,
    u16* __restrict__ xb, float* __restrict__ srow, float* __restrict__ lxa)
{
    const int m = blockIdx.x;
    const int tid = threadIdx.x;
    const float4* xrow4 = (const float4*)(x + (size_t)m * IN_F);
    const float4* la4 = (const float4*)lora_A;
    float ssum = 0.f;
    float acc[RANK];
#pragma unroll
    for (int r = 0; r < RANK; ++r) acc[r] = 0.f;
#pragma unroll
    for (int t = 0; t < IN_F / (256 * 4); ++t) {
        int i4 = t * 256 + tid;
        float4 v = xrow4[i4];
        ssum += v.x + v.y + v.z + v.w;
        union { u16 h[4]; uint2 u2; } pk;
        pk.h[0] = f32_to_bf16_rne(v.x);
        pk.h[1] = f32_to_bf16_rne(v.y);
        pk.h[2] = f32_to_bf16_rne(v.z);
        pk.h[3] = f32_to_bf16_rne(v.w);
        *(uint2*)&xb[(size_t)m * IN_F + i4 * 4] = pk.u2;
#pragma unroll
        for (int r = 0; r < RANK; ++r) {
            float4 a = la4[r * (IN_F / 4) + i4];
            acc[r] = fmaf(v.x, a.x, fmaf(v.y, a.y, fmaf(v.z, a.z, fmaf(v.w, a.w, acc[r]))));
        }
    }
#pragma unroll
    for (int off = 32; off > 0; off >>= 1) {
        ssum += __shfl_down(ssum, off, 64);
#pragma unroll
        for (int r = 0; r < RANK; ++r) acc[r] += __shfl_down(acc[r], off, 64);
    }
    __shared__ float red[4][RANK + 1];
    int wv = tid >> 6, ln = tid & 63;
    if (ln == 0) {
        red[wv][0] = ssum;
#pragma unroll
        for (int r = 0; r < RANK; ++r) red[wv][1 + r] = acc[r];
    }
    __syncthreads();
    if (tid == 0) srow[m] = red[0][0] + red[1][0] + red[2][0] + red[3][0];
    if (tid < RANK)
        lxa[m * RANK + tid] = red[0][1 + tid] + red[1][1 + tid] + red[2][1 + tid] + red[3][1 + tid];
}

// ------- pack: Tw2[wq][col], wq = 2t+p covers words (4t+p, 4t+2+p) ---------
// One uint2 load gives a lane BOTH its kk=0 (.x) and kk=1 (.y) words for
// iteration t at parity p = lane>>5. LDS-tiled, coalesced both sides.
__global__ __launch_bounds__(256) void pack_kernel(
    const uint32_t* __restrict__ Tp, uint2* __restrict__ Tw2)
{
    __shared__ uint32_t s[64][NWORDS + 1];
    const int tid = threadIdx.x;
    const int col0 = blockIdx.x * 64;
#pragma unroll 8
    for (int i = 0; i < 64; ++i) {
        int idx = i * 256 + tid;
        s[idx >> 8][idx & 255] = Tp[(size_t)(col0 + (idx >> 8)) * NWORDS + (idx & 255)];
    }
    __syncthreads();
    const int c = tid & 63;
#pragma unroll 8
    for (int q = 0; q < 32; ++q) {
        int wq = q * 4 + (tid >> 6);          // 0..127
        int t = wq >> 1, p = wq & 1;
        uint2 v;
        v.x = s[c][4 * t + p];
        v.y = s[c][4 * t + 2 + p];
        Tw2[(size_t)wq * OUT_F + col0 + c] = v;
    }
}

// ---------------- ternary decode (VERIFIED R1-R12) ----------------
__device__ __forceinline__ short8 decode8(uint32_t h)
{
    uint32_t selA = (h & 0xFu) | ((h & 0xF0u) << 12);
    selA = (selA | (selA << 6)) & 0x03030303u;
    uint32_t h2 = h >> 8;
    uint32_t selB = (h2 & 0xFu) | ((h2 & 0xF0u) << 12);
    selB = (selB | (selB << 6)) & 0x03030303u;
    uint32_t hiA = __builtin_amdgcn_perm(0u, 0x003F00BFu, selA);
    uint32_t loA = __builtin_amdgcn_perm(0u, 0x00800080u, selA);
    uint32_t hiB = __builtin_amdgcn_perm(0u, 0x003F00BFu, selB);
    uint32_t loB = __builtin_amdgcn_perm(0u, 0x00800080u, selB);
    union { uint32_t u[4]; short8 s; } cvt;
    cvt.u[0] = __builtin_amdgcn_perm(hiA, loA, 0x05010400u);
    cvt.u[1] = __builtin_amdgcn_perm(hiA, loA, 0x07030602u);
    cvt.u[2] = __builtin_amdgcn_perm(hiB, loB, 0x05010400u);
    cvt.u[3] = __builtin_amdgcn_perm(hiB, loB, 0x07030602u);
    return cvt.s;
}

#define WAITV6 asm volatile("s_waitcnt vmcnt(6)" ::: "memory")
#define WAITV0 asm volatile("s_waitcnt vmcnt(0)" ::: "memory")
#define BAR    __builtin_amdgcn_s_barrier()
#define SCHED0 __builtin_amdgcn_sched_barrier(0)

struct Frags { short8 af[4][2]; };
struct BW    { uint2 w[2]; };      // per-lane B words for nt=0,1

// --- fused GEMM: 128x64 tile, 4 waves (64x32, mt4/nt2), 3-buf A in LDS,
// B in registers (coalesced Tw2 loads, prefetch 2 ahead), split-K=2.
// Per iter j: loadB(j+2) | stage A(j+2) | compute(j) | WAITV(6) | BAR |
// rdfrags(j+1).  vmcnt FIFO at WAITV: [B(j+1)2 A(j+1)4 B(j+2)2 A(j+2)4]=12
// -> retire 6 = B(j+1)+A(j+1); A stage->wait distance = 1 iter, B = 2 iters.
// Buf (j+2)%3 overwrite-safe: last read end of iter j-2, BAR(j-1) intervenes.
// z==0 blocks add the affine term (bias + mu*s + 2*LoRA) in the epilogue.
__global__ __launch_bounds__(256, 3) void gemm_kernel(
    const u16* __restrict__ xb, const uint2* __restrict__ Tw2,
    const float* __restrict__ alpha, const float* __restrict__ mu,
    const float* __restrict__ bias, const float* __restrict__ lora_B,
    const float* __restrict__ srow, const float* __restrict__ lxa,
    float* __restrict__ out)
{
    __shared__ __align__(16) u16 ldsA[3][BM * BK];       // 3 x 16 KB

    const int tid = threadIdx.x;
    const int lane = tid & 63;
    const int wave = tid >> 6;
    const int wm = wave >> 1, wn = wave & 1;
    const int mb = blockIdx.y * BM;
    const int nb = blockIdx.x * BN;
    const int z = blockIdx.z;

    const int bshift = ((lane >> 4) & 1) * 16;

    // A-stage: 1024 x 16B chunks; 4/thread; XOR-swizzled SOURCE, linear dest
    const u16* asrc[4];
    int adst[4];
#pragma unroll
    for (int i = 0; i < 4; ++i) {
        int q = i * 256 + tid;
        int row = q >> 3;
        int scc = (q & 7) ^ (row & 7);
        asrc[i] = xb + (size_t)(mb + row) * IN_F + z * K_PER + scc * 8;
        adst[i] = q * 8;
    }
    // B: per-lane uint2 pointers, one per nt; row = Tw2 column
    const uint2* bptr[2];
#pragma unroll
    for (int nt = 0; nt < 2; ++nt)
        bptr[nt] = Tw2 + (size_t)(z * 64 + (lane >> 5)) * OUT_F
                       + nb + wn * 32 + nt * 16 + (lane & 15);

    int aoff[4][2];
#pragma unroll
    for (int mt = 0; mt < 4; ++mt)
#pragma unroll
        for (int kk = 0; kk < 2; ++kk) {
            int r = wm * 64 + mt * 16 + (lane & 15);
            int sc = kk * 4 + (lane >> 4);
            aoff[mt][kk] = (r * 8 + (sc ^ (r & 7))) * 8;
        }

    floatx4 acc[4][2] = {};

    auto stage = [&](int buf, int jt) {
#pragma unroll
        for (int i = 0; i < 4; ++i) {
            __builtin_amdgcn_global_load_lds(
                (const __attribute__((address_space(1))) void*)(asrc[i] + jt * BK),
                (__attribute__((address_space(3))) void*)(&ldsA[buf][adst[i]]),
                16, 0, 0);
        }
    };
    auto loadB = [&](BW& b, int jt) {
#pragma unroll
        for (int nt = 0; nt < 2; ++nt)
            b.w[nt] = bptr[nt][(size_t)(2 * jt) * OUT_F];
    };
    auto rdfrags = [&](int buf, Frags& F) {
#pragma unroll
        for (int mt = 0; mt < 4; ++mt)
#pragma unroll
            for (int kk = 0; kk < 2; ++kk)
                F.af[mt][kk] = *(const short8*)&ldsA[buf][aoff[mt][kk]];
    };
    auto compute = [&](Frags& F, BW& b) {
        __builtin_amdgcn_s_setprio(1);
#pragma unroll
        for (int kk = 0; kk < 2; ++kk) {
#pragma unroll
            for (int nt = 0; nt < 2; ++nt) {
                uint32_t w = kk ? b.w[nt].y : b.w[nt].x;
                short8 bf = decode8((w >> bshift) & 0xFFFFu);
#pragma unroll
                for (int mt = 0; mt < 4; ++mt)
                    acc[mt][nt] = __builtin_amdgcn_mfma_f32_16x16x32_bf16(
                        F.af[mt][kk], bf, acc[mt][nt], 0, 0, 0);
            }
        }
        __builtin_amdgcn_s_setprio(0);
    };

    Frags fA, fB;
    BW bw0, bw1, bw2;

    // prologue -> entering state for j=0: outstanding [B(1)2, A(1)4]
    stage(0, 0); loadB(bw0, 0);
    WAITV0; BAR;
    rdfrags(0, fA); SCHED0;
    loadB(bw1, 1); stage(1, 1);

    // steady: j = 0..29, unroll 6 (buf%3 x parity cycles)
#pragma unroll 1
    for (int u = 0; u < 5; ++u) {
        const int j = u * 6;
        loadB(bw2, j + 2); stage(2, j + 2); SCHED0; compute(fA, bw0); WAITV6; BAR; rdfrags(1, fB); SCHED0;
        loadB(bw0, j + 3); stage(0, j + 3); SCHED0; compute(fB, bw1); WAITV6; BAR; rdfrags(2, fA); SCHED0;
        loadB(bw1, j + 4); stage(1, j + 4); SCHED0; compute(fA, bw2); WAITV6; BAR; rdfrags(0, fB); SCHED0;
        loadB(bw2, j + 5); stage(2, j + 5); SCHED0; compute(fB, bw0); WAITV6; BAR; rdfrags(1, fA); SCHED0;
        loadB(bw0, j + 6); stage(0, j + 6); SCHED0; compute(fA, bw1); WAITV6; BAR; rdfrags(2, fB); SCHED0;
        loadB(bw1, j + 7); stage(1, j + 7); SCHED0; compute(fB, bw2); WAITV6; BAR; rdfrags(0, fA); SCHED0;
    }
    // j = 30: outstanding [B(31)2, A(31)4]; compute(30)=fA,bw0; drain; buf 31%3=1
    compute(fA, bw0); WAITV0; BAR; rdfrags(1, fB); SCHED0;
    // j = 31
    compute(fB, bw1);

    // ---- epilogue: atomicAdd; z==0 also adds affine base ----
    const int o0 = nb + wn * 32 + (lane & 15);
    const int m0 = mb + wm * 64 + ((lane >> 4) * 4);
    float al[2] = { alpha[o0], alpha[o0 + 16] };

    if (z == 0) {
        float muv[2] = { mu[o0], mu[o0 + 16] };
        float bi[2]  = { bias[o0], bias[o0 + 16] };
        float Brow[2][RANK];
#pragma unroll
        for (int nt = 0; nt < 2; ++nt) {
            const float4* b4 = (const float4*)(lora_B + (size_t)(o0 + nt * 16) * RANK);
#pragma unroll
            for (int r4 = 0; r4 < RANK / 4; ++r4) {
                float4 v = b4[r4];
                Brow[nt][r4 * 4 + 0] = v.x; Brow[nt][r4 * 4 + 1] = v.y;
                Brow[nt][r4 * 4 + 2] = v.z; Brow[nt][r4 * 4 + 3] = v.w;
            }
        }
#pragma unroll
        for (int mt = 0; mt < 4; ++mt) {
#pragma unroll
            for (int rg = 0; rg < 4; ++rg) {
                int m = m0 + mt * 16 + rg;
                float sm = srow[m];
                float lx[RANK];
                const float4* l4 = (const float4*)(lxa + (size_t)m * RANK);
#pragma unroll
                for (int r4 = 0; r4 < RANK / 4; ++r4) {
                    float4 v = l4[r4];
                    lx[r4 * 4 + 0] = v.x; lx[r4 * 4 + 1] = v.y;
                    lx[r4 * 4 + 2] = v.z; lx[r4 * 4 + 3] = v.w;
                }
#pragma unroll
                for (int nt = 0; nt < 2; ++nt) {
                    float lora = 0.f;
#pragma unroll
                    for (int r = 0; r < RANK; ++r) lora = fmaf(lx[r], Brow[nt][r], lora);
                    atomicAdd(&out[(size_t)m * OUT_F + o0 + nt * 16],
                              al[nt] * acc[mt][nt][rg] + muv[nt] * sm + 2.0f * lora + bi[nt]);
                }
            }
        }
    } else {
#pragma unroll
        for (int mt = 0; mt < 4; ++mt) {
#pragma unroll
            for (int rg = 0; rg < 4; ++rg) {
                int m = m0 + mt * 16 + rg;
#pragma unroll
                for (int nt = 0; nt < 2; ++nt)
                    atomicAdd(&out[(size_t)m * OUT_F + o0 + nt * 16],
                              al[nt] * acc[mt][nt][rg]);
            }
        }
    }
}

extern "C" void kernel_launch(void* const* d_in, const int* in_sizes, int n_in,
                              void* d_out, int out_size, void* d_ws, size_t ws_size,
                              hipStream_t stream)
{
    const float* x = (const float*)d_in[0];
    const uint32_t* Tp = (const uint32_t*)d_in[1];
    const float* alpha = (const float*)d_in[2];
    const float* mu = (const float*)d_in[3];
    const float* bias = (const float*)d_in[4];
    const float* lora_A = (const float*)d_in[5];
    const float* lora_B = (const float*)d_in[6];
    float* out = (float*)d_out;

    u16* xb = (u16*)d_ws;                                    // 2 MB
    float* srow = (float*)((char*)d_ws + (size_t)M_ROWS * IN_F * 2);
    float* lxa = (float*)((char*)d_ws + (size_t)M_ROWS * IN_F * 2 + 4096);
    uint2* Tw2 = (uint2*)((char*)d_ws + (4u << 20));         // 11.3 MB at +4MB

    hipMemsetAsync(out, 0, (size_t)out_size * sizeof(float), stream);
    prep_kernel<<<dim3(M_ROWS), dim3(256), 0, stream>>>(x, lora_A, xb, srow, lxa);
    pack_kernel<<<dim3(OUT_F / 64), dim3(256), 0, stream>>>(Tp, Tw2);
    gemm_kernel<<<dim3(OUT_F / BN, M_ROWS / BM, KSPLIT), dim3(256), 0, stream>>>(
        xb, Tw2, alpha, mu, bias, lora_B, srow, lxa, out);
}